// Round 1
// baseline (157.623 us; speedup 1.0000x reference)
//
#include <hip/hip_runtime.h>
#include <math.h>

#define NB 16
#define HH 256
#define WW 256
#define NC 128
#define KTOP 8
#define RAD 5
#define CAP 2048
#define TILE_ROWS 16
#define HALO 5
#define LROWS (TILE_ROWS + 2*HALO)   // 26

// ---------------- workspace layout (bytes) ----------------
// 0    : int      cand_count[16]    (zeroed each call)
// 64   : unsigned wmmax_bits[16]    (zeroed each call; 0 == 0.0f)
// 128  : float    gmax[16]
// 192  : float    pr[16][8]
// 704  : float    pc[16][8]
// 1216 : float    pw[16][8]         (prob * valid)
// 2048 : float    cand_score[16][CAP]
// 2048+131072 : int cand_idx[16][CAP]
// total ~264 KB

// ---------- K1: per-batch global max of heatmap ----------
__global__ void k_gmax(const float* __restrict__ hm, float* __restrict__ gmax) {
    int b = blockIdx.x;
    const float4* p = (const float4*)(hm + (size_t)b * HH * WW);
    float m = -INFINITY;
    for (int i = threadIdx.x; i < HH * WW / 4; i += 256) {
        float4 v = p[i];
        m = fmaxf(m, fmaxf(fmaxf(v.x, v.y), fmaxf(v.z, v.w)));
    }
    __shared__ float red[256];
    red[threadIdx.x] = m;
    __syncthreads();
    for (int s = 128; s > 0; s >>= 1) {
        if (threadIdx.x < s) red[threadIdx.x] = fmaxf(red[threadIdx.x], red[threadIdx.x + s]);
        __syncthreads();
    }
    if (threadIdx.x == 0) gmax[b] = red[0];
}

// ---------- K2: separable 11x11 NMS + candidate collection ----------
__global__ void k_peaks(const float* __restrict__ hm, const float* __restrict__ gmax,
                        int* __restrict__ cand_count,
                        float* __restrict__ cand_score, int* __restrict__ cand_idx) {
    int b    = blockIdx.x >> 4;     // 16 tiles per batch
    int tile = blockIdx.x & 15;
    int row0 = tile * TILE_ROWS;

    __shared__ float t[LROWS][WW];
    __shared__ float hx[LROWS][WW];

    const float* p = hm + (size_t)b * HH * WW;
    for (int i = threadIdx.x; i < LROWS * WW; i += 256) {
        int lr = i >> 8, col = i & 255;
        int gr = row0 - HALO + lr;
        t[lr][col] = (gr >= 0 && gr < HH) ? p[gr * WW + col] : -INFINITY;
    }
    __syncthreads();

    // horizontal window-11 max (clip == -inf padding)
    for (int i = threadIdx.x; i < LROWS * WW; i += 256) {
        int lr = i >> 8, col = i & 255;
        int c0 = col - RAD < 0 ? 0 : col - RAD;
        int c1 = col + RAD > WW - 1 ? WW - 1 : col + RAD;
        float m = -INFINITY;
        for (int c = c0; c <= c1; ++c) m = fmaxf(m, t[lr][c]);
        hx[lr][col] = m;
    }
    __syncthreads();

    float thresh = 0.05f * gmax[b];
    for (int i = threadIdx.x; i < TILE_ROWS * WW; i += 256) {
        int lr = (i >> 8) + HALO, col = i & 255;
        float v = t[lr][col];
        float m = -INFINITY;
        for (int r = lr - RAD; r <= lr + RAD; ++r) m = fmaxf(m, hx[r][col]);
        if (v >= m && v >= thresh) {
            int pos = atomicAdd(&cand_count[b], 1);
            if (pos < CAP) {
                cand_score[b * CAP + pos] = v;
                cand_idx[b * CAP + pos]   = (row0 + lr - HALO) * WW + col;
            }
        }
    }
}

// ---------- K3: per-batch top-8 (stable tie-break) + softmax + feature gather ----------
__global__ void k_topk(const float* __restrict__ fmap,
                       const int* __restrict__ cand_count,
                       const float* __restrict__ cand_score, const int* __restrict__ cand_idx,
                       float* __restrict__ out_feats, float* __restrict__ out_pos,
                       float* __restrict__ out_probs, float* __restrict__ out_valid,
                       float* __restrict__ pr, float* __restrict__ pc, float* __restrict__ pw) {
    int b = blockIdx.x;
    int count = cand_count[b];
    if (count > CAP) count = CAP;

    __shared__ float cv[CAP];
    __shared__ int   ci[CAP];
    for (int i = threadIdx.x; i < count; i += 256) {
        cv[i] = cand_score[b * CAP + i];
        ci[i] = cand_idx[b * CAP + i];
    }
    __syncthreads();

    __shared__ float rv[256];
    __shared__ int   ri[256];
    __shared__ int   rp[256];
    __shared__ float sel_v[KTOP];
    __shared__ int   sel_i[KTOP];
    __shared__ int   sel_p[KTOP];

    for (int k = 0; k < KTOP; ++k) {
        float bv = -INFINITY; int bi = 0x7fffffff; int bp = -1;
        for (int i = threadIdx.x; i < count; i += 256) {
            float v = cv[i]; int idx = ci[i];
            if (v > bv || (v == bv && idx < bi)) { bv = v; bi = idx; bp = i; }
        }
        rv[threadIdx.x] = bv; ri[threadIdx.x] = bi; rp[threadIdx.x] = bp;
        __syncthreads();
        for (int s = 128; s > 0; s >>= 1) {
            if (threadIdx.x < s) {
                float v = rv[threadIdx.x + s]; int idx = ri[threadIdx.x + s];
                if (v > rv[threadIdx.x] || (v == rv[threadIdx.x] && idx < ri[threadIdx.x])) {
                    rv[threadIdx.x] = v; ri[threadIdx.x] = idx; rp[threadIdx.x] = rp[threadIdx.x + s];
                }
            }
            __syncthreads();
        }
        if (threadIdx.x == 0) {
            sel_v[k] = rv[0]; sel_i[k] = ri[0]; sel_p[k] = rp[0];
            if (rp[0] >= 0) cv[rp[0]] = -INFINITY;   // remove from pool
        }
        __syncthreads();
    }

    __shared__ float s_r[KTOP], s_c[KTOP];

    if (threadIdx.x == 0) {
        // padding path (fewer than 8 candidates): score -1e9, idx = smallest non-peak flat idx
        int next = 0;
        for (int k = 0; k < KTOP; ++k) {
            if (sel_p[k] < 0) {
                for (;;) {
                    bool taken = false;
                    for (int j = 0; j < count; ++j) if (ci[j] == next) { taken = true; break; }
                    if (!taken) break;
                    ++next;
                }
                sel_i[k] = next;
                sel_v[k] = -1.0e9f;
                ++next;
            }
        }
        // softmax over the 8 scores
        float m = sel_v[0];
        for (int k = 1; k < KTOP; ++k) m = fmaxf(m, sel_v[k]);
        float e[KTOP], s = 0.f;
        for (int k = 0; k < KTOP; ++k) { e[k] = expf(sel_v[k] - m); s += e[k]; }
        for (int k = 0; k < KTOP; ++k) {
            float prob = e[k] / s;
            int idx = sel_i[k];
            float rrow = (float)(idx / WW);
            float rcol = (float)(idx % WW);
            float vld  = sel_v[k] > -1.0e8f ? 1.f : 0.f;
            out_pos[(b * KTOP + k) * 2 + 0] = rrow;
            out_pos[(b * KTOP + k) * 2 + 1] = rcol;
            out_probs[b * KTOP + k] = prob;
            out_valid[b * KTOP + k] = vld;
            pr[b * KTOP + k] = rrow;
            pc[b * KTOP + k] = rcol;
            pw[b * KTOP + k] = prob * vld;
            s_r[k] = rrow; s_c[k] = rcol;
        }
    }
    __syncthreads();

    // bilinear feature gather (positions are integers -> degenerates to f00, but do full 4-tap)
    for (int t = threadIdx.x; t < KTOP * NC; t += 256) {
        int k  = t >> 7;
        int ch = t & 127;
        float rr = s_r[k], cc = s_c[k];
        float r0f = floorf(rr), c0f = floorf(cc);
        float wr = rr - r0f, wc = cc - c0f;
        int r0 = min(max((int)r0f, 0), HH - 1);
        int r1 = min(max((int)r0f + 1, 0), HH - 1);
        int c0 = min(max((int)c0f, 0), WW - 1);
        int c1 = min(max((int)c0f + 1, 0), WW - 1);
        const float* fb = fmap + ((size_t)b * NC + ch) * HH * WW;
        float f00 = fb[r0 * WW + c0], f01 = fb[r0 * WW + c1];
        float f10 = fb[r1 * WW + c0], f11 = fb[r1 * WW + c1];
        out_feats[(size_t)b * KTOP * NC + t] =
            f00 * (1 - wr) * (1 - wc) + f01 * (1 - wr) * wc +
            f10 * wr * (1 - wc) + f11 * wr * wc;
    }
}

// shared gaussian-sum helper
__device__ __forceinline__ float wm_at(int pix, const float* spr, const float* spc, const float* spw) {
    float fi = (float)(pix >> 8);
    float fj = (float)(pix & 255);
    float wmv = 0.f;
#pragma unroll
    for (int k = 0; k < KTOP; ++k) {
        float dr = fi - spr[k];
        float dc = fj - spc[k];
        wmv += spw[k] * __expf(-(dr * dr + dc * dc) * (1.0f / 50.0f));
    }
    return wmv;
}

// ---------- K4: per-batch max of weight_map ----------
__global__ void k_wmmax(const float* __restrict__ pr, const float* __restrict__ pc,
                        const float* __restrict__ pw, unsigned* __restrict__ wmmax) {
    int b = blockIdx.y;
    __shared__ float spr[KTOP], spc[KTOP], spw[KTOP];
    if (threadIdx.x < KTOP) {
        spr[threadIdx.x] = pr[b * KTOP + threadIdx.x];
        spc[threadIdx.x] = pc[b * KTOP + threadIdx.x];
        spw[threadIdx.x] = pw[b * KTOP + threadIdx.x];
    }
    __syncthreads();
    float m = 0.f;
    int pix0 = blockIdx.x * (256 * 4);
    for (int u = 0; u < 4; ++u) {
        int pix = pix0 + u * 256 + threadIdx.x;
        m = fmaxf(m, wm_at(pix, spr, spc, spw));
    }
    __shared__ float red[256];
    red[threadIdx.x] = m;
    __syncthreads();
    for (int s = 128; s > 0; s >>= 1) {
        if (threadIdx.x < s) red[threadIdx.x] = fmaxf(red[threadIdx.x], red[threadIdx.x + s]);
        __syncthreads();
    }
    if (threadIdx.x == 0) atomicMax(&wmmax[b], __float_as_uint(red[0]));  // wm >= 0
}

// ---------- K5: normalize + reweight ----------
__global__ void k_reweight(const float* __restrict__ hm,
                           const float* __restrict__ pr, const float* __restrict__ pc,
                           const float* __restrict__ pw, const unsigned* __restrict__ wmmax,
                           float* __restrict__ out) {
    int b = blockIdx.y;
    __shared__ float spr[KTOP], spc[KTOP], spw[KTOP];
    if (threadIdx.x < KTOP) {
        spr[threadIdx.x] = pr[b * KTOP + threadIdx.x];
        spc[threadIdx.x] = pc[b * KTOP + threadIdx.x];
        spw[threadIdx.x] = pw[b * KTOP + threadIdx.x];
    }
    __syncthreads();
    int pix = blockIdx.x * 256 + threadIdx.x;
    float wmv = wm_at(pix, spr, spc, spw);
    float mx = __uint_as_float(wmmax[b]);
    size_t off = (size_t)b * HH * WW + pix;
    out[off] = hm[off] * (0.5f + 0.5f * wmv / (mx + 1e-8f));
}

extern "C" void kernel_launch(void* const* d_in, const int* in_sizes, int n_in,
                              void* d_out, int out_size, void* d_ws, size_t ws_size,
                              hipStream_t stream) {
    const float* heatmap = (const float*)d_in[0];
    const float* fmap    = (const float*)d_in[1];

    float* out = (float*)d_out;
    // output layout (flat fp32, return order):
    float* out_reweighted = out;                       // 16*1*256*256 = 1048576
    float* out_feats      = out + 1048576;             // 16*8*128     = 16384
    float* out_pos        = out + 1048576 + 16384;     // 16*8*2       = 256
    float* out_probs      = out_pos + 256;             // 16*8         = 128
    float* out_valid      = out_probs + 128;           // 16*8         = 128

    char* ws = (char*)d_ws;
    int*      cand_count = (int*)ws;
    unsigned* wmmax      = (unsigned*)(ws + 64);
    float*    gmax       = (float*)(ws + 128);
    float*    pr         = (float*)(ws + 192);
    float*    pc         = (float*)(ws + 704);
    float*    pw         = (float*)(ws + 1216);
    float*    cand_score = (float*)(ws + 2048);
    int*      cand_idx   = (int*)(ws + 2048 + NB * CAP * 4);

    // zero cand_count + wmmax (0 bits == 0.0f)
    hipMemsetAsync(ws, 0, 128, stream);

    k_gmax<<<NB, 256, 0, stream>>>(heatmap, gmax);
    k_peaks<<<NB * 16, 256, 0, stream>>>(heatmap, gmax, cand_count, cand_score, cand_idx);
    k_topk<<<NB, 256, 0, stream>>>(fmap, cand_count, cand_score, cand_idx,
                                   out_feats, out_pos, out_probs, out_valid, pr, pc, pw);
    k_wmmax<<<dim3(64, NB), 256, 0, stream>>>(pr, pc, pw, wmmax);
    k_reweight<<<dim3(256, NB), 256, 0, stream>>>(heatmap, pr, pc, pw, wmmax, out_reweighted);
}

// Round 2
// 61.568 us; speedup vs baseline: 2.5601x; 2.5601x over previous
//
#include <hip/hip_runtime.h>
#include <math.h>

#define NB 16
#define HH 256
#define WW 256
#define NC 128
#define KTOP 8
#define RAD 5
#define TCAP 125
#define TILE_ROWS 16
#define HALO 5
#define LROWS (TILE_ROWS + 2*HALO)   // 26

// ---------------- workspace layout (bytes), total ~258 KB ----------------
// 0      : float tv[16][16][TCAP]   per-tile candidate scores (256000 B for tv+ti)
// 128000 : int   ti[16][16][TCAP]   per-tile candidate flat indices
// 256000 : int   tcount[16][16]
// 257024 : float gpart[16][16]      per-tile max of heatmap
// 258048 : float pr[16][8]
// 258560 : float pc[16][8]
// 259072 : float pw[16][8]
// 259584 : float wmpart[16][64]

// ---------- K1: separable 11x11 NMS, per-tile candidates + per-tile max ----------
__global__ void k_nms(const float* __restrict__ hm,
                      float* __restrict__ gpart, int* __restrict__ tcount,
                      float* __restrict__ tv, int* __restrict__ ti) {
    int b    = blockIdx.x >> 4;
    int tile = blockIdx.x & 15;
    int row0 = tile * TILE_ROWS;
    int tid  = threadIdx.x;

    __shared__ float t[LROWS][WW];
    __shared__ float hx[LROWS][WW];
    __shared__ int   cnt;
    __shared__ float red[256];
    if (tid == 0) cnt = 0;

    // vectorized tile load (with -inf row padding)
    const float4* p4 = (const float4*)(hm + (size_t)b * HH * WW);
    float4 nf = make_float4(-INFINITY, -INFINITY, -INFINITY, -INFINITY);
    for (int i = tid; i < LROWS * (WW / 4); i += 256) {
        int lr = i >> 6, c4 = i & 63;
        int gr = row0 - HALO + lr;
        float4 v = (gr >= 0 && gr < HH) ? p4[gr * 64 + c4] : nf;
        ((float4*)&t[lr][0])[c4] = v;
    }
    __syncthreads();

    // horizontal window-11 max (col clipping == -inf padding)
    for (int i = tid; i < LROWS * WW; i += 256) {
        int lr = i >> 8, col = i & 255;
        int c0 = col - RAD < 0 ? 0 : col - RAD;
        int c1 = col + RAD > WW - 1 ? WW - 1 : col + RAD;
        float m = -INFINITY;
        for (int c = c0; c <= c1; ++c) m = fmaxf(m, t[lr][c]);
        hx[lr][col] = m;
    }
    __syncthreads();

    // vertical pass + candidate collect + per-thread tile max
    float tmax = -INFINITY;
    int tile_id = b * 16 + tile;
    for (int i = tid; i < TILE_ROWS * WW; i += 256) {
        int lr = (i >> 8) + HALO, col = i & 255;
        float v = t[lr][col];
        tmax = fmaxf(tmax, v);
        float m = -INFINITY;
        for (int r = lr - RAD; r <= lr + RAD; ++r) m = fmaxf(m, hx[r][col]);
        if (v >= m) {  // NMS peak (score threshold applied later, once gmax known)
            int pos = atomicAdd(&cnt, 1);
            if (pos < TCAP) {
                tv[tile_id * TCAP + pos] = v;
                ti[tile_id * TCAP + pos] = (row0 + lr - HALO) * WW + col;
            }
        }
    }
    red[tid] = tmax;
    __syncthreads();
    for (int s = 128; s > 0; s >>= 1) {
        if (tid < s) red[tid] = fmaxf(red[tid], red[tid + s]);
        __syncthreads();
    }
    if (tid == 0) {
        gpart[tile_id]  = red[0];
        tcount[tile_id] = cnt;
    }
}

// ---------- K2: gmax reduce + threshold + top-8 + softmax + feature gather ----------
__global__ void k_select(const float* __restrict__ fmap,
                         const float* __restrict__ gpart, const int* __restrict__ tcount,
                         const float* __restrict__ tv, const int* __restrict__ ti,
                         float* __restrict__ out_feats, float* __restrict__ out_pos,
                         float* __restrict__ out_probs, float* __restrict__ out_valid,
                         float* __restrict__ pr, float* __restrict__ pc, float* __restrict__ pw) {
    int b = blockIdx.x, tid = threadIdx.x;

    __shared__ float cv[16 * TCAP];
    __shared__ int   ci[16 * TCAP];
    __shared__ int   cnt;
    __shared__ int   sct[16];
    __shared__ float sg;
    if (tid == 0) {
        cnt = 0;
        float g = -INFINITY;
        for (int j = 0; j < 16; ++j) g = fmaxf(g, gpart[b * 16 + j]);
        sg = g;
    }
    if (tid < 16) {
        int c = tcount[b * 16 + tid];
        sct[tid] = c > TCAP ? TCAP : c;
    }
    __syncthreads();
    float thresh = 0.05f * sg;

    // gather + threshold-filter candidates into LDS
    for (int i = tid; i < 16 * TCAP; i += 256) {
        int j = i / TCAP, p = i - j * TCAP;
        if (p < sct[j]) {
            float v = tv[(b * 16 + j) * TCAP + p];
            if (v >= thresh) {
                int pos = atomicAdd(&cnt, 1);
                cv[pos] = v;
                ci[pos] = ti[(b * 16 + j) * TCAP + p];
            }
        }
    }
    __syncthreads();
    int count = cnt;

    __shared__ float wv[4]; __shared__ int wi[4]; __shared__ int wp[4];
    __shared__ float sel_v[KTOP]; __shared__ int sel_i[KTOP]; __shared__ int sel_p[KTOP];

    for (int k = 0; k < KTOP; ++k) {
        float bv = -INFINITY; int bi = 0x7fffffff; int bp = -1;
        for (int i = tid; i < count; i += 256) {
            float v = cv[i]; int idx = ci[i];
            if (v > bv || (v == bv && idx < bi)) { bv = v; bi = idx; bp = i; }
        }
        // wave-level reduce (no barriers)
        for (int s = 1; s < 64; s <<= 1) {
            float v = __shfl_xor(bv, s); int idx = __shfl_xor(bi, s); int p = __shfl_xor(bp, s);
            if (v > bv || (v == bv && idx < bi)) { bv = v; bi = idx; bp = p; }
        }
        if ((tid & 63) == 0) { int w = tid >> 6; wv[w] = bv; wi[w] = bi; wp[w] = bp; }
        __syncthreads();
        if (tid == 0) {
            for (int j = 1; j < 4; ++j)
                if (wv[j] > wv[0] || (wv[j] == wv[0] && wi[j] < wi[0])) {
                    wv[0] = wv[j]; wi[0] = wi[j]; wp[0] = wp[j];
                }
            sel_v[k] = wv[0]; sel_i[k] = wi[0]; sel_p[k] = wp[0];
            if (wp[0] >= 0) cv[wp[0]] = -INFINITY;   // remove from pool
        }
        __syncthreads();
    }

    __shared__ float s_r[KTOP], s_c[KTOP];
    if (tid == 0) {
        // padding path (fewer than 8 above-threshold peaks): score -1e9,
        // idx = smallest flat idx that is not a selected-eligible peak
        int next = 0;
        for (int k = 0; k < KTOP; ++k) {
            if (sel_p[k] < 0) {
                for (;;) {
                    bool taken = false;
                    for (int j = 0; j < count; ++j) if (ci[j] == next) { taken = true; break; }
                    if (!taken) break;
                    ++next;
                }
                sel_i[k] = next;
                sel_v[k] = -1.0e9f;
                ++next;
            }
        }
        float m = sel_v[0];
        for (int k = 1; k < KTOP; ++k) m = fmaxf(m, sel_v[k]);
        float e[KTOP], s = 0.f;
        for (int k = 0; k < KTOP; ++k) { e[k] = expf(sel_v[k] - m); s += e[k]; }
        for (int k = 0; k < KTOP; ++k) {
            float prob = e[k] / s;
            int idx = sel_i[k];
            float rrow = (float)(idx / WW);
            float rcol = (float)(idx % WW);
            float vld  = sel_v[k] > -1.0e8f ? 1.f : 0.f;
            out_pos[(b * KTOP + k) * 2 + 0] = rrow;
            out_pos[(b * KTOP + k) * 2 + 1] = rcol;
            out_probs[b * KTOP + k] = prob;
            out_valid[b * KTOP + k] = vld;
            pr[b * KTOP + k] = rrow;
            pc[b * KTOP + k] = rcol;
            pw[b * KTOP + k] = prob * vld;
            s_r[k] = rrow; s_c[k] = rcol;
        }
    }
    __syncthreads();

    // bilinear feature gather (positions integral -> f00 dominates; full 4-tap kept)
    for (int t = tid; t < KTOP * NC; t += 256) {
        int k  = t >> 7;
        int ch = t & 127;
        float rr = s_r[k], cc = s_c[k];
        float r0f = floorf(rr), c0f = floorf(cc);
        float wr = rr - r0f, wc = cc - c0f;
        int r0 = min(max((int)r0f, 0), HH - 1);
        int r1 = min(max((int)r0f + 1, 0), HH - 1);
        int c0 = min(max((int)c0f, 0), WW - 1);
        int c1 = min(max((int)c0f + 1, 0), WW - 1);
        const float* fb = fmap + ((size_t)b * NC + ch) * HH * WW;
        float f00 = fb[r0 * WW + c0], f01 = fb[r0 * WW + c1];
        float f10 = fb[r1 * WW + c0], f11 = fb[r1 * WW + c1];
        out_feats[(size_t)b * KTOP * NC + t] =
            f00 * (1 - wr) * (1 - wc) + f01 * (1 - wr) * wc +
            f10 * wr * (1 - wc) + f11 * wr * wc;
    }
}

// shared gaussian-sum helper
__device__ __forceinline__ float wm_at(int pix, const float* spr, const float* spc, const float* spw) {
    float fi = (float)(pix >> 8);
    float fj = (float)(pix & 255);
    float wmv = 0.f;
#pragma unroll
    for (int k = 0; k < KTOP; ++k) {
        float dr = fi - spr[k];
        float dc = fj - spc[k];
        wmv += spw[k] * __expf(-(dr * dr + dc * dc) * 0.02f);
    }
    return wmv;
}

// ---------- K3: per-block partial max of weight_map (no atomics) ----------
__global__ void k_wmmax(const float* __restrict__ pr, const float* __restrict__ pc,
                        const float* __restrict__ pw, float* __restrict__ wmpart) {
    int b = blockIdx.y, blk = blockIdx.x, tid = threadIdx.x;
    __shared__ float spr[KTOP], spc[KTOP], spw[KTOP];
    if (tid < KTOP) {
        spr[tid] = pr[b * KTOP + tid];
        spc[tid] = pc[b * KTOP + tid];
        spw[tid] = pw[b * KTOP + tid];
    }
    __syncthreads();
    float m = 0.f;
    int pix0 = blk * 1024;
    for (int u = 0; u < 4; ++u)
        m = fmaxf(m, wm_at(pix0 + u * 256 + tid, spr, spc, spw));
    __shared__ float red[256];
    red[tid] = m;
    __syncthreads();
    for (int s = 128; s > 0; s >>= 1) {
        if (tid < s) red[tid] = fmaxf(red[tid], red[tid + s]);
        __syncthreads();
    }
    if (tid == 0) wmpart[b * 64 + blk] = red[0];
}

// ---------- K4: reduce partials + normalize + reweight (float4, 4 px/thread) ----------
__global__ void k_reweight(const float* __restrict__ hm,
                           const float* __restrict__ pr, const float* __restrict__ pc,
                           const float* __restrict__ pw, const float* __restrict__ wmpart,
                           float* __restrict__ out) {
    int b = blockIdx.y, blk = blockIdx.x, tid = threadIdx.x;
    __shared__ float spr[KTOP], spc[KTOP], spw[KTOP];
    __shared__ float red[64];
    if (tid < KTOP) {
        spr[tid] = pr[b * KTOP + tid];
        spc[tid] = pc[b * KTOP + tid];
        spw[tid] = pw[b * KTOP + tid];
    }
    if (tid < 64) red[tid] = wmpart[b * 64 + tid];
    __syncthreads();
    if (tid < 32) red[tid] = fmaxf(red[tid], red[tid + 32]); __syncthreads();
    if (tid < 16) red[tid] = fmaxf(red[tid], red[tid + 16]); __syncthreads();
    if (tid < 8)  red[tid] = fmaxf(red[tid], red[tid + 8]);  __syncthreads();
    if (tid < 4)  red[tid] = fmaxf(red[tid], red[tid + 4]);  __syncthreads();
    if (tid < 2)  red[tid] = fmaxf(red[tid], red[tid + 2]);  __syncthreads();
    if (tid < 1)  red[tid] = fmaxf(red[tid], red[tid + 1]);  __syncthreads();
    float inv = 0.5f / (red[0] + 1e-8f);

    int idx4 = blk * 256 + tid;                    // float4 index within batch
    const float4* h4 = (const float4*)(hm + (size_t)b * HH * WW);
    float4*       o4 = (float4*)(out + (size_t)b * HH * WW);
    float4 h = h4[idx4];
    int pix = idx4 * 4;
    float4 o;
    o.x = h.x * (0.5f + wm_at(pix + 0, spr, spc, spw) * inv);
    o.y = h.y * (0.5f + wm_at(pix + 1, spr, spc, spw) * inv);
    o.z = h.z * (0.5f + wm_at(pix + 2, spr, spc, spw) * inv);
    o.w = h.w * (0.5f + wm_at(pix + 3, spr, spc, spw) * inv);
    o4[idx4] = o;
}

extern "C" void kernel_launch(void* const* d_in, const int* in_sizes, int n_in,
                              void* d_out, int out_size, void* d_ws, size_t ws_size,
                              hipStream_t stream) {
    const float* heatmap = (const float*)d_in[0];
    const float* fmap    = (const float*)d_in[1];

    float* out = (float*)d_out;
    float* out_reweighted = out;                       // 16*1*256*256 = 1048576
    float* out_feats      = out + 1048576;             // 16*8*128     = 16384
    float* out_pos        = out + 1048576 + 16384;     // 16*8*2       = 256
    float* out_probs      = out_pos + 256;             // 16*8         = 128
    float* out_valid      = out_probs + 128;           // 16*8         = 128

    char* ws = (char*)d_ws;
    float* tv     = (float*)(ws + 0);
    int*   ti     = (int*)  (ws + 128000);
    int*   tcount = (int*)  (ws + 256000);
    float* gpart  = (float*)(ws + 257024);
    float* pr     = (float*)(ws + 258048);
    float* pc     = (float*)(ws + 258560);
    float* pw     = (float*)(ws + 259072);
    float* wmpart = (float*)(ws + 259584);

    k_nms<<<NB * 16, 256, 0, stream>>>(heatmap, gpart, tcount, tv, ti);
    k_select<<<NB, 256, 0, stream>>>(fmap, gpart, tcount, tv, ti,
                                     out_feats, out_pos, out_probs, out_valid, pr, pc, pw);
    k_wmmax<<<dim3(64, NB), 256, 0, stream>>>(pr, pc, pw, wmpart);
    k_reweight<<<dim3(64, NB), 256, 0, stream>>>(heatmap, pr, pc, pw, wmpart, out_reweighted);
}